// Round 1
// baseline (1226.712 us; speedup 1.0000x reference)
//
#include <hip/hip_runtime.h>
#include <hip/hip_bf16.h>

// MoE top-2, T=32768 tokens, D=1024, E=8.
// Pipeline: gate(+x->bf16) -> wconv(transpose W->bf16) -> scan -> scatter -> grouped GEMM (bf16 MFMA, atomic combine).

typedef __attribute__((ext_vector_type(8))) short short8_t;
typedef __attribute__((ext_vector_type(4))) float f32x4_t;

#define GLOAD_LDS16(g, l)                                                                     \
  __builtin_amdgcn_global_load_lds((const __attribute__((address_space(1))) unsigned int*)(g), \
                                   (__attribute__((address_space(3))) unsigned int*)(l), 16, 0, 0)

__device__ __forceinline__ unsigned short f2bf(float f) {
  union { __hip_bfloat16 h; unsigned short u; } c;
  c.h = __float2bfloat16(f);
  return c.u;
}

// ---------------- gate: fp32 logits, top-2 softmax, ranks; also x -> bf16 ----------------
__global__ __launch_bounds__(256) void gate_kernel(
    const float* __restrict__ x, const float* __restrict__ gw,
    unsigned short* __restrict__ xb, int* __restrict__ ctrl,
    int* __restrict__ tok_e, int* __restrict__ tok_r, float* __restrict__ tok_w)
{
  int wid = threadIdx.x >> 6, lane = threadIdx.x & 63;
  int t = (blockIdx.x << 2) + wid;                      // one wave per token
  const float4* x4 = (const float4*)(x + ((size_t)t << 10));
  const float4* g4 = (const float4*)gw;                 // gw is [1024][8] row-major
  unsigned long long* xb8 = (unsigned long long*)(xb + ((size_t)t << 10));
  float lg[8] = {0.f,0.f,0.f,0.f,0.f,0.f,0.f,0.f};
  #pragma unroll
  for (int c = 0; c < 4; ++c) {
    int d4 = (c << 6) + lane;                           // float4 index within the row
    float4 v = x4[d4];
    unsigned long long pk = (unsigned long long)f2bf(v.x)
                          | ((unsigned long long)f2bf(v.y) << 16)
                          | ((unsigned long long)f2bf(v.z) << 32)
                          | ((unsigned long long)f2bf(v.w) << 48);
    xb8[d4] = pk;
    float xs[4] = {v.x, v.y, v.z, v.w};
    #pragma unroll
    for (int j = 0; j < 4; ++j) {
      int d = (d4 << 2) + j;
      float4 ga = g4[d << 1];
      float4 gb = g4[(d << 1) + 1];
      lg[0] += xs[j]*ga.x; lg[1] += xs[j]*ga.y; lg[2] += xs[j]*ga.z; lg[3] += xs[j]*ga.w;
      lg[4] += xs[j]*gb.x; lg[5] += xs[j]*gb.y; lg[6] += xs[j]*gb.z; lg[7] += xs[j]*gb.w;
    }
  }
  #pragma unroll
  for (int e = 0; e < 8; ++e) {
    float v = lg[e];
    #pragma unroll
    for (int s = 32; s > 0; s >>= 1) v += __shfl_xor(v, s, 64);
    lg[e] = v;
  }
  if (lane == 0) {
    float m0 = lg[0], m1 = -3.4e38f; int e0 = 0, e1 = 0;
    #pragma unroll
    for (int e = 1; e < 8; ++e) {                       // strict '>' => first index wins (matches jax top_k)
      float v = lg[e];
      if (v > m0) { m1 = m0; e1 = e0; m0 = v; e0 = e; }
      else if (v > m1) { m1 = v; e1 = e; }
    }
    float p1 = 1.0f / (1.0f + expf(m0 - m1));           // softmax of [m0, m1]
    float p0 = 1.0f - p1;
    int r0 = atomicAdd(&ctrl[e0], 1);
    int r1 = atomicAdd(&ctrl[e1], 1);
    int i0 = t << 1;
    tok_e[i0]   = e0; tok_r[i0]   = r0; tok_w[i0]   = p0;
    tok_e[i0+1] = e1; tok_r[i0+1] = r1; tok_w[i0+1] = p1;
  }
}

// ---------------- expert_w fp32 [e][k][n] -> bf16 transposed Wt[e][n][k] ----------------
__global__ __launch_bounds__(256) void wconv_kernel(const float* __restrict__ w,
                                                    unsigned short* __restrict__ wt)
{
  __shared__ float tile[32][33];
  const float* we = w + ((size_t)blockIdx.z << 20);
  unsigned short* wte = wt + ((size_t)blockIdx.z << 20);
  int k0 = blockIdx.x << 5, n0 = blockIdx.y << 5;
  for (int i = threadIdx.x; i < 1024; i += 256) {
    int k = i >> 5, n = i & 31;
    tile[k][n] = we[(size_t)(k0 + k) * 1024 + n0 + n];
  }
  __syncthreads();
  for (int i = threadIdx.x; i < 1024; i += 256) {
    int n = i >> 5, k = i & 31;
    wte[(size_t)(n0 + n) * 1024 + k0 + k] = f2bf(tile[k][n]);
  }
}

// ---------------- scan: offsets + per-expert M-block prefix ----------------
__global__ void scan_kernel(int* ctrl) {
  if (threadIdx.x == 0) {
    int off = 0, boff = 0;
    for (int e = 0; e < 8; ++e) {
      int c = ctrl[e];
      ctrl[8 + e] = off; off += c;
      ctrl[16 + e] = boff; boff += (c + 127) >> 7;
    }
    ctrl[24] = boff;   // total M-blocks
  }
}

// ---------------- scatter (t,k) -> dense slots ----------------
__global__ __launch_bounds__(256) void scatter_kernel(
    const int* __restrict__ ctrl, const int* __restrict__ tok_e, const int* __restrict__ tok_r,
    const float* __restrict__ tok_w, int* __restrict__ slot_token, float* __restrict__ slot_w)
{
  int i = (blockIdx.x << 8) + threadIdx.x;
  int e = tok_e[i];
  int slot = ctrl[8 + e] + tok_r[i];
  slot_token[slot] = i >> 1;
  slot_w[slot] = tok_w[i];
}

// ---------------- grouped GEMM: per expert, gathered rows; 128x128 tile, BK=32 ----------------
__global__ __launch_bounds__(256) void moe_gemm(
    const unsigned short* __restrict__ xb, const unsigned short* __restrict__ wt,
    const float* __restrict__ bias, const int* __restrict__ ctrl,
    const int* __restrict__ slot_token, const float* __restrict__ slot_w,
    float* __restrict__ out, int total_slots)
{
  __shared__ unsigned short Alds[128 * 32];
  __shared__ unsigned short Blds[128 * 32];
  __shared__ int   tokid[128];
  __shared__ float wrow[128];

  int by = blockIdx.y;
  if (by >= ctrl[24]) return;
  int e = 0;
  #pragma unroll
  for (int i = 1; i < 8; ++i) if (by >= ctrl[16 + i]) e = i;
  int mblk = by - ctrl[16 + e];
  int cnt  = ctrl[e];
  int off  = ctrl[8 + e];
  int slot0 = off + (mblk << 7);
  int rows_valid = cnt - (mblk << 7); if (rows_valid > 128) rows_valid = 128;

  int tid = threadIdx.x;
  if (tid < 128) {
    int s = slot0 + tid; if (s > total_slots - 1) s = total_slots - 1;
    tokid[tid] = slot_token[s];
    wrow[tid]  = slot_w[s];
  }
  __syncthreads();

  int lane = tid & 63, w = tid >> 6;
  int bn0 = blockIdx.x << 7;

  // staging chunks: 512 x 16B per tile; chunk c -> row c>>2, k-offset (c&3)*8
  int c0 = (w << 6) + lane, c1 = c0 + 256;
  const unsigned short* gA0 = xb + ((size_t)tokid[c0 >> 2] << 10) + ((c0 & 3) << 3);
  const unsigned short* gA1 = xb + ((size_t)tokid[c1 >> 2] << 10) + ((c1 & 3) << 3);
  const unsigned short* wte = wt + ((size_t)e << 20);
  const unsigned short* gB0 = wte + ((size_t)(bn0 + (c0 >> 2)) << 10) + ((c0 & 3) << 3);
  const unsigned short* gB1 = wte + ((size_t)(bn0 + (c1 >> 2)) << 10) + ((c1 & 3) << 3);
  unsigned short* lA0 = &Alds[(size_t)(w << 6) * 8];          // wave-uniform LDS dests
  unsigned short* lA1 = &Alds[(size_t)((w << 6) + 256) * 8];
  unsigned short* lB0 = &Blds[(size_t)(w << 6) * 8];
  unsigned short* lB1 = &Blds[(size_t)((w << 6) + 256) * 8];

  int wr = w >> 1, wc = w & 1;
  int l15 = lane & 15, lh8 = (lane >> 4) << 3;
  f32x4_t acc[4][4] = {};

  for (int kk = 0; kk < 1024; kk += 32) {
    GLOAD_LDS16(gA0 + kk, lA0);
    GLOAD_LDS16(gA1 + kk, lA1);
    GLOAD_LDS16(gB0 + kk, lB0);
    GLOAD_LDS16(gB1 + kk, lB1);
    __syncthreads();                                     // drains vmcnt -> staging visible
    short8_t aF[4], bF[4];
    #pragma unroll
    for (int m = 0; m < 4; ++m)
      aF[m] = *(const short8_t*)&Alds[(((wr << 6) + (m << 4) + l15) << 5) + lh8];
    #pragma unroll
    for (int n = 0; n < 4; ++n)
      bF[n] = *(const short8_t*)&Blds[(((wc << 6) + (n << 4) + l15) << 5) + lh8];
    #pragma unroll
    for (int m = 0; m < 4; ++m)
      #pragma unroll
      for (int n = 0; n < 4; ++n)
        acc[m][n] = __builtin_amdgcn_mfma_f32_16x16x32_bf16(aF[m], bF[n], acc[m][n], 0, 0, 0);
    __syncthreads();                                     // all waves done reading before overwrite
  }

  const float* be = bias + (e << 10);
  #pragma unroll
  for (int n = 0; n < 4; ++n) {
    int dout = bn0 + (wc << 6) + (n << 4) + l15;
    float bv = be[dout];
    #pragma unroll
    for (int m = 0; m < 4; ++m) {
      int rbase = (wr << 6) + (m << 4) + ((lane >> 4) << 2);
      #pragma unroll
      for (int r = 0; r < 4; ++r) {
        int row = rbase + r;
        if (row < rows_valid) {
          float val = wrow[row] * (acc[m][n][r] + bv);
          atomicAdd(&out[((size_t)tokid[row] << 10) + dout], val);
        }
      }
    }
  }
}

extern "C" void kernel_launch(void* const* d_in, const int* in_sizes, int n_in,
                              void* d_out, int out_size, void* d_ws, size_t ws_size,
                              hipStream_t stream) {
  (void)n_in; (void)ws_size;
  const float* x  = (const float*)d_in[0];
  const float* gw = (const float*)d_in[1];
  const float* ew = (const float*)d_in[2];
  const float* eb = (const float*)d_in[3];
  int T  = in_sizes[0] >> 10;   // 32768
  int T2 = T << 1;              // 65536 slots

  // workspace layout (~82 MB)
  char* wsb = (char*)d_ws;
  unsigned short* xb = (unsigned short*)wsb;
  size_t off = (size_t)T * 1024 * 2;                    // x bf16: 64 MB
  unsigned short* wt = (unsigned short*)(wsb + off);
  off += (size_t)8 * 1024 * 1024 * 2;                   // Wt bf16: 16 MB
  int* ctrl = (int*)(wsb + off); off += 256;            // counts[8], offsets[8], bp[9]
  int* tok_e = (int*)(wsb + off); off += (size_t)T2 * 4;
  int* tok_r = (int*)(wsb + off); off += (size_t)T2 * 4;
  float* tok_w = (float*)(wsb + off); off += (size_t)T2 * 4;
  int* slot_token = (int*)(wsb + off); off += (size_t)T2 * 4;
  float* slot_w = (float*)(wsb + off); off += (size_t)T2 * 4;

  float* out = (float*)d_out;

  hipMemsetAsync(ctrl, 0, 64 * sizeof(int), stream);
  hipMemsetAsync(d_out, 0, (size_t)out_size * sizeof(float), stream);
  gate_kernel<<<T / 4, 256, 0, stream>>>(x, gw, xb, ctrl, tok_e, tok_r, tok_w);
  wconv_kernel<<<dim3(32, 32, 8), 256, 0, stream>>>(ew, wt);
  scan_kernel<<<1, 64, 0, stream>>>(ctrl);
  scatter_kernel<<<T2 / 256, 256, 0, stream>>>(ctrl, tok_e, tok_r, tok_w, slot_token, slot_w);
  moe_gemm<<<dim3(8, 520), 256, 0, stream>>>(xb, wt, eb, ctrl, slot_token, slot_w, out, T2);
}

// Round 2
// 528.981 us; speedup vs baseline: 2.3190x; 2.3190x over previous
//
#include <hip/hip_runtime.h>
#include <hip/hip_bf16.h>

// MoE top-2, T=32768 tokens, D=1024, E=8.
// Pipeline: gate(4 tok/wave, no atomics) -> hist(LDS ranks) -> scan(wave-scan) -> scatter
//           -> wconv(W->bf16 transposed) -> grouped GEMM (bf16 MFMA, atomic combine).

typedef __attribute__((ext_vector_type(8))) short short8_t;
typedef __attribute__((ext_vector_type(4))) float f32x4_t;

#define GLOAD_LDS16(g, l)                                                                     \
  __builtin_amdgcn_global_load_lds((const __attribute__((address_space(1))) unsigned int*)(g), \
                                   (__attribute__((address_space(3))) unsigned int*)(l), 16, 0, 0)

__device__ __forceinline__ unsigned short f2bf(float f) {
  union { __hip_bfloat16 h; unsigned short u; } c;
  c.h = __float2bfloat16(f);
  return c.u;
}

// ---------------- gate: 4 tokens/wave; fp32 logits, top-2 softmax; x -> bf16; NO atomics ----
__global__ __launch_bounds__(256) void gate_kernel(
    const float* __restrict__ x, const float* __restrict__ gw,
    unsigned short* __restrict__ xb,
    int* __restrict__ tok_e, float* __restrict__ tok_w)
{
  int wid = threadIdx.x >> 6, lane = threadIdx.x & 63;
  int t0 = (blockIdx.x << 4) + (wid << 2);              // 4 tokens per wave
  const float4* g4 = (const float4*)gw;                 // gw is [1024][8] row-major
  float lg[4][8] = {};
  #pragma unroll
  for (int c = 0; c < 4; ++c) {
    int d4 = (c << 6) + lane;                           // float4 index within a row
    float4 ga[4], gb[4];
    #pragma unroll
    for (int j = 0; j < 4; ++j) {                       // gw rows for this lane's 4 d's
      int d = (d4 << 2) + j;
      ga[j] = g4[d << 1];
      gb[j] = g4[(d << 1) + 1];
    }
    #pragma unroll
    for (int t = 0; t < 4; ++t) {                       // reuse gw regs across 4 tokens
      const float4* x4 = (const float4*)(x + ((size_t)(t0 + t) << 10));
      float4 v = x4[d4];
      unsigned long long pk = (unsigned long long)f2bf(v.x)
                            | ((unsigned long long)f2bf(v.y) << 16)
                            | ((unsigned long long)f2bf(v.z) << 32)
                            | ((unsigned long long)f2bf(v.w) << 48);
      ((unsigned long long*)(xb + ((size_t)(t0 + t) << 10)))[d4] = pk;
      float xs[4] = {v.x, v.y, v.z, v.w};
      #pragma unroll
      for (int j = 0; j < 4; ++j) {
        lg[t][0] += xs[j]*ga[j].x; lg[t][1] += xs[j]*ga[j].y;
        lg[t][2] += xs[j]*ga[j].z; lg[t][3] += xs[j]*ga[j].w;
        lg[t][4] += xs[j]*gb[j].x; lg[t][5] += xs[j]*gb[j].y;
        lg[t][6] += xs[j]*gb[j].z; lg[t][7] += xs[j]*gb[j].w;
      }
    }
  }
  #pragma unroll
  for (int t = 0; t < 4; ++t)
    #pragma unroll
    for (int e = 0; e < 8; ++e) {
      float v = lg[t][e];
      #pragma unroll
      for (int s = 32; s > 0; s >>= 1) v += __shfl_xor(v, s, 64);
      lg[t][e] = v;
    }
  if (lane < 4) {                                       // lane t finalizes token t0+t
    int t = t0 + lane;
    float m0 = lg[lane][0], m1 = -3.4e38f; int e0 = 0, e1 = 0;
    #pragma unroll
    for (int e = 1; e < 8; ++e) {                       // strict '>' matches jax top_k ties
      float v = lg[lane][e];
      if (v > m0) { m1 = m0; e1 = e0; m0 = v; e0 = e; }
      else if (v > m1) { m1 = v; e1 = e; }
    }
    float p1 = 1.0f / (1.0f + expf(m0 - m1));
    float p0 = 1.0f - p1;
    int i0 = t << 1;
    tok_e[i0]   = e0; tok_w[i0]   = p0;
    tok_e[i0+1] = e1; tok_w[i0+1] = p1;
  }
}

// ---------------- hist: per-256-entry chunk, LDS histogram + local rank ----------------
__global__ __launch_bounds__(256) void hist_kernel(
    const int* __restrict__ tok_e, int* __restrict__ tok_r, int* __restrict__ chunkhist)
{
  __shared__ int lh[8];
  if (threadIdx.x < 8) lh[threadIdx.x] = 0;
  __syncthreads();
  int i = (blockIdx.x << 8) + threadIdx.x;
  int e = tok_e[i];
  tok_r[i] = atomicAdd(&lh[e], 1);                      // LDS atomic: fast, uncontended-ish
  __syncthreads();
  if (threadIdx.x < 8) chunkhist[(blockIdx.x << 3) + threadIdx.x] = lh[threadIdx.x];
}

// ---------------- scan: 8 waves, wave e scans expert e across 256 chunks ----------------
__global__ __launch_bounds__(512) void scan_kernel(
    const int* __restrict__ chunkhist, int* __restrict__ base, int* __restrict__ ctrl)
{
  __shared__ int h[2048];
  __shared__ int bx[2048];
  __shared__ int tot[8], eoff[8];
  for (int i = threadIdx.x; i < 2048; i += 512) h[i] = chunkhist[i];
  __syncthreads();
  int wid = threadIdx.x >> 6, lane = threadIdx.x & 63;
  int running = 0;
  #pragma unroll
  for (int b = 0; b < 4; ++b) {                         // 4 batches of 64 chunks
    int c = (b << 6) + lane;
    int orig = h[(c << 3) + wid];
    int v = orig;
    #pragma unroll
    for (int s = 1; s < 64; s <<= 1) {
      int u = __shfl_up(v, s, 64);
      if (lane >= s) v += u;
    }
    bx[(c << 3) + wid] = running + v - orig;            // exclusive, expert-local
    running += __shfl(v, 63, 64);                       // batch total
  }
  if (lane == 0) tot[wid] = running;
  __syncthreads();
  if (threadIdx.x == 0) {
    int off = 0, boff = 0;
    #pragma unroll
    for (int e = 0; e < 8; ++e) {
      ctrl[e] = tot[e];
      ctrl[8 + e] = off; eoff[e] = off; off += tot[e];
      ctrl[16 + e] = boff; boff += (tot[e] + 127) >> 7;
    }
    ctrl[24] = boff;                                    // total M-blocks
  }
  __syncthreads();
  for (int i = threadIdx.x; i < 2048; i += 512) base[i] = bx[i] + eoff[i & 7];
}

// ---------------- scatter (t,k) -> dense slots ----------------
__global__ __launch_bounds__(256) void scatter_kernel(
    const int* __restrict__ tok_e, const int* __restrict__ tok_r, const float* __restrict__ tok_w,
    const int* __restrict__ base, int* __restrict__ slot_token, float* __restrict__ slot_w)
{
  int i = (blockIdx.x << 8) + threadIdx.x;
  int e = tok_e[i];
  int slot = base[((i >> 8) << 3) + e] + tok_r[i];
  slot_token[slot] = i >> 1;
  slot_w[slot] = tok_w[i];
}

// ---------------- expert_w fp32 [e][k][n] -> bf16 transposed Wt[e][n][k] ----------------
__global__ __launch_bounds__(256) void wconv_kernel(const float* __restrict__ w,
                                                    unsigned short* __restrict__ wt)
{
  __shared__ float tile[32][33];
  const float* we = w + ((size_t)blockIdx.z << 20);
  unsigned short* wte = wt + ((size_t)blockIdx.z << 20);
  int k0 = blockIdx.x << 5, n0 = blockIdx.y << 5;
  for (int i = threadIdx.x; i < 1024; i += 256) {
    int k = i >> 5, n = i & 31;
    tile[k][n] = we[(size_t)(k0 + k) * 1024 + n0 + n];
  }
  __syncthreads();
  for (int i = threadIdx.x; i < 1024; i += 256) {
    int n = i >> 5, k = i & 31;
    wte[(size_t)(n0 + n) * 1024 + k0 + k] = f2bf(tile[k][n]);
  }
}

// ---------------- grouped GEMM: per expert, gathered rows; 128x128 tile, BK=32 ----------------
__global__ __launch_bounds__(256) void moe_gemm(
    const unsigned short* __restrict__ xb, const unsigned short* __restrict__ wt,
    const float* __restrict__ bias, const int* __restrict__ ctrl,
    const int* __restrict__ slot_token, const float* __restrict__ slot_w,
    float* __restrict__ out, int total_slots)
{
  __shared__ unsigned short Alds[128 * 32];
  __shared__ unsigned short Blds[128 * 32];
  __shared__ int   tokid[128];
  __shared__ float wrow[128];

  int by = blockIdx.y;
  if (by >= ctrl[24]) return;
  int e = 0;
  #pragma unroll
  for (int i = 1; i < 8; ++i) if (by >= ctrl[16 + i]) e = i;
  int mblk = by - ctrl[16 + e];
  int cnt  = ctrl[e];
  int off  = ctrl[8 + e];
  int slot0 = off + (mblk << 7);
  int rows_valid = cnt - (mblk << 7); if (rows_valid > 128) rows_valid = 128;

  int tid = threadIdx.x;
  if (tid < 128) {
    int s = slot0 + tid; if (s > total_slots - 1) s = total_slots - 1;
    tokid[tid] = slot_token[s];
    wrow[tid]  = slot_w[s];
  }
  __syncthreads();

  int lane = tid & 63, w = tid >> 6;
  int bn0 = blockIdx.x << 7;

  // staging chunks: 512 x 16B per tile; chunk c -> row c>>2, k-offset (c&3)*8
  int c0 = (w << 6) + lane, c1 = c0 + 256;
  const unsigned short* gA0 = xb + ((size_t)tokid[c0 >> 2] << 10) + ((c0 & 3) << 3);
  const unsigned short* gA1 = xb + ((size_t)tokid[c1 >> 2] << 10) + ((c1 & 3) << 3);
  const unsigned short* wte = wt + ((size_t)e << 20);
  const unsigned short* gB0 = wte + ((size_t)(bn0 + (c0 >> 2)) << 10) + ((c0 & 3) << 3);
  const unsigned short* gB1 = wte + ((size_t)(bn0 + (c1 >> 2)) << 10) + ((c1 & 3) << 3);
  unsigned short* lA0 = &Alds[(size_t)(w << 6) * 8];          // wave-uniform LDS dests
  unsigned short* lA1 = &Alds[(size_t)((w << 6) + 256) * 8];
  unsigned short* lB0 = &Blds[(size_t)(w << 6) * 8];
  unsigned short* lB1 = &Blds[(size_t)((w << 6) + 256) * 8];

  int wr = w >> 1, wc = w & 1;
  int l15 = lane & 15, lh8 = (lane >> 4) << 3;
  f32x4_t acc[4][4] = {};

  for (int kk = 0; kk < 1024; kk += 32) {
    GLOAD_LDS16(gA0 + kk, lA0);
    GLOAD_LDS16(gA1 + kk, lA1);
    GLOAD_LDS16(gB0 + kk, lB0);
    GLOAD_LDS16(gB1 + kk, lB1);
    __syncthreads();                                     // drains vmcnt -> staging visible
    short8_t aF[4], bF[4];
    #pragma unroll
    for (int m = 0; m < 4; ++m)
      aF[m] = *(const short8_t*)&Alds[(((wr << 6) + (m << 4) + l15) << 5) + lh8];
    #pragma unroll
    for (int n = 0; n < 4; ++n)
      bF[n] = *(const short8_t*)&Blds[(((wc << 6) + (n << 4) + l15) << 5) + lh8];
    #pragma unroll
    for (int m = 0; m < 4; ++m)
      #pragma unroll
      for (int n = 0; n < 4; ++n)
        acc[m][n] = __builtin_amdgcn_mfma_f32_16x16x32_bf16(aF[m], bF[n], acc[m][n], 0, 0, 0);
    __syncthreads();                                     // all waves done reading before overwrite
  }

  const float* be = bias + (e << 10);
  #pragma unroll
  for (int n = 0; n < 4; ++n) {
    int dout = bn0 + (wc << 6) + (n << 4) + l15;
    float bv = be[dout];
    #pragma unroll
    for (int m = 0; m < 4; ++m) {
      int rbase = (wr << 6) + (m << 4) + ((lane >> 4) << 2);
      #pragma unroll
      for (int r = 0; r < 4; ++r) {
        int row = rbase + r;
        if (row < rows_valid) {
          float val = wrow[row] * (acc[m][n][r] + bv);
          atomicAdd(&out[((size_t)tokid[row] << 10) + dout], val);
        }
      }
    }
  }
}

extern "C" void kernel_launch(void* const* d_in, const int* in_sizes, int n_in,
                              void* d_out, int out_size, void* d_ws, size_t ws_size,
                              hipStream_t stream) {
  (void)n_in; (void)ws_size;
  const float* x  = (const float*)d_in[0];
  const float* gw = (const float*)d_in[1];
  const float* ew = (const float*)d_in[2];
  const float* eb = (const float*)d_in[3];
  int T  = in_sizes[0] >> 10;   // 32768
  int T2 = T << 1;              // 65536 slots

  // workspace layout (~82 MB)
  char* wsb = (char*)d_ws;
  unsigned short* xb = (unsigned short*)wsb;
  size_t off = (size_t)T * 1024 * 2;                    // x bf16: 64 MB
  unsigned short* wt = (unsigned short*)(wsb + off);
  off += (size_t)8 * 1024 * 1024 * 2;                   // Wt bf16: 16 MB
  int* ctrl = (int*)(wsb + off); off += 256;            // counts[8], offsets[8], bp[9]
  int* tok_e = (int*)(wsb + off); off += (size_t)T2 * 4;
  int* tok_r = (int*)(wsb + off); off += (size_t)T2 * 4;
  float* tok_w = (float*)(wsb + off); off += (size_t)T2 * 4;
  int* slot_token = (int*)(wsb + off); off += (size_t)T2 * 4;
  float* slot_w = (float*)(wsb + off); off += (size_t)T2 * 4;
  int* chunkhist = (int*)(wsb + off); off += 2048 * 4;  // 256 chunks x 8 experts
  int* base = (int*)(wsb + off); off += 2048 * 4;

  float* out = (float*)d_out;

  hipMemsetAsync(d_out, 0, (size_t)out_size * sizeof(float), stream);
  gate_kernel<<<T / 16, 256, 0, stream>>>(x, gw, xb, tok_e, tok_w);
  wconv_kernel<<<dim3(32, 32, 8), 256, 0, stream>>>(ew, wt);
  hist_kernel<<<T2 / 256, 256, 0, stream>>>(tok_e, tok_r, chunkhist);
  scan_kernel<<<1, 512, 0, stream>>>(chunkhist, base, ctrl);
  scatter_kernel<<<T2 / 256, 256, 0, stream>>>(tok_e, tok_r, tok_w, base, slot_token, slot_w);
  moe_gemm<<<dim3(8, 520), 256, 0, stream>>>(xb, wt, eb, ctrl, slot_token, slot_w, out, T2);
}

// Round 3
// 439.616 us; speedup vs baseline: 2.7904x; 1.2033x over previous
//
#include <hip/hip_runtime.h>
#include <hip/hip_bf16.h>

// MoE top-2, T=32768 tokens, D=1024, E=8.
// Pipeline: gate(4 tok/wave) -> hist -> scan -> scatter(+inverse map) -> wconv
//           -> grouped GEMM (bf16 MFMA, swizzled LDS, ybuf stores) -> combine.

typedef __attribute__((ext_vector_type(8))) short short8_t;
typedef __attribute__((ext_vector_type(4))) float f32x4_t;

#define GLOAD_LDS16(g, l)                                                                     \
  __builtin_amdgcn_global_load_lds((const __attribute__((address_space(1))) unsigned int*)(g), \
                                   (__attribute__((address_space(3))) unsigned int*)(l), 16, 0, 0)

__device__ __forceinline__ unsigned short f2bf(float f) {
  union { __hip_bfloat16 h; unsigned short u; } c;
  c.h = __float2bfloat16(f);
  return c.u;
}

// ---------------- gate: 4 tokens/wave; fp32 logits, top-2 softmax; x -> bf16 ----------------
__global__ __launch_bounds__(256) void gate_kernel(
    const float* __restrict__ x, const float* __restrict__ gw,
    unsigned short* __restrict__ xb,
    int* __restrict__ tok_e, float* __restrict__ tok_w)
{
  int wid = threadIdx.x >> 6, lane = threadIdx.x & 63;
  int t0 = (blockIdx.x << 4) + (wid << 2);              // 4 tokens per wave
  const float4* g4 = (const float4*)gw;                 // gw is [1024][8] row-major
  float lg[4][8] = {};
  #pragma unroll
  for (int c = 0; c < 4; ++c) {
    int d4 = (c << 6) + lane;                           // float4 index within a row
    float4 ga[4], gb[4];
    #pragma unroll
    for (int j = 0; j < 4; ++j) {
      int d = (d4 << 2) + j;
      ga[j] = g4[d << 1];
      gb[j] = g4[(d << 1) + 1];
    }
    #pragma unroll
    for (int t = 0; t < 4; ++t) {                       // reuse gw regs across 4 tokens
      const float4* x4 = (const float4*)(x + ((size_t)(t0 + t) << 10));
      float4 v = x4[d4];
      unsigned long long pk = (unsigned long long)f2bf(v.x)
                            | ((unsigned long long)f2bf(v.y) << 16)
                            | ((unsigned long long)f2bf(v.z) << 32)
                            | ((unsigned long long)f2bf(v.w) << 48);
      ((unsigned long long*)(xb + ((size_t)(t0 + t) << 10)))[d4] = pk;
      float xs[4] = {v.x, v.y, v.z, v.w};
      #pragma unroll
      for (int j = 0; j < 4; ++j) {
        lg[t][0] += xs[j]*ga[j].x; lg[t][1] += xs[j]*ga[j].y;
        lg[t][2] += xs[j]*ga[j].z; lg[t][3] += xs[j]*ga[j].w;
        lg[t][4] += xs[j]*gb[j].x; lg[t][5] += xs[j]*gb[j].y;
        lg[t][6] += xs[j]*gb[j].z; lg[t][7] += xs[j]*gb[j].w;
      }
    }
  }
  #pragma unroll
  for (int t = 0; t < 4; ++t)
    #pragma unroll
    for (int e = 0; e < 8; ++e) {
      float v = lg[t][e];
      #pragma unroll
      for (int s = 32; s > 0; s >>= 1) v += __shfl_xor(v, s, 64);
      lg[t][e] = v;
    }
  if (lane < 4) {                                       // lane t finalizes token t0+t
    int t = t0 + lane;
    float m0 = lg[lane][0], m1 = -3.4e38f; int e0 = 0, e1 = 0;
    #pragma unroll
    for (int e = 1; e < 8; ++e) {                       // strict '>' matches jax top_k ties
      float v = lg[lane][e];
      if (v > m0) { m1 = m0; e1 = e0; m0 = v; e0 = e; }
      else if (v > m1) { m1 = v; e1 = e; }
    }
    float p1 = 1.0f / (1.0f + expf(m0 - m1));
    float p0 = 1.0f - p1;
    int i0 = t << 1;
    tok_e[i0]   = e0; tok_w[i0]   = p0;
    tok_e[i0+1] = e1; tok_w[i0+1] = p1;
  }
}

// ---------------- hist: per-256-entry chunk, LDS histogram + local rank ----------------
__global__ __launch_bounds__(256) void hist_kernel(
    const int* __restrict__ tok_e, int* __restrict__ tok_r, int* __restrict__ chunkhist)
{
  __shared__ int lh[8];
  if (threadIdx.x < 8) lh[threadIdx.x] = 0;
  __syncthreads();
  int i = (blockIdx.x << 8) + threadIdx.x;
  int e = tok_e[i];
  tok_r[i] = atomicAdd(&lh[e], 1);
  __syncthreads();
  if (threadIdx.x < 8) chunkhist[(blockIdx.x << 3) + threadIdx.x] = lh[threadIdx.x];
}

// ---------------- scan: 8 waves, wave e scans expert e across 256 chunks ----------------
__global__ __launch_bounds__(512) void scan_kernel(
    const int* __restrict__ chunkhist, int* __restrict__ base, int* __restrict__ ctrl)
{
  __shared__ int h[2048];
  __shared__ int bx[2048];
  __shared__ int tot[8], eoff[8];
  for (int i = threadIdx.x; i < 2048; i += 512) h[i] = chunkhist[i];
  __syncthreads();
  int wid = threadIdx.x >> 6, lane = threadIdx.x & 63;
  int running = 0;
  #pragma unroll
  for (int b = 0; b < 4; ++b) {
    int c = (b << 6) + lane;
    int orig = h[(c << 3) + wid];
    int v = orig;
    #pragma unroll
    for (int s = 1; s < 64; s <<= 1) {
      int u = __shfl_up(v, s, 64);
      if (lane >= s) v += u;
    }
    bx[(c << 3) + wid] = running + v - orig;            // exclusive, expert-local
    running += __shfl(v, 63, 64);
  }
  if (lane == 0) tot[wid] = running;
  __syncthreads();
  if (threadIdx.x == 0) {
    int off = 0, boff = 0;
    #pragma unroll
    for (int e = 0; e < 8; ++e) {
      ctrl[e] = tot[e];
      ctrl[8 + e] = off; eoff[e] = off; off += tot[e];
      ctrl[16 + e] = boff; boff += (tot[e] + 127) >> 7;
    }
    ctrl[24] = boff;
  }
  __syncthreads();
  for (int i = threadIdx.x; i < 2048; i += 512) base[i] = bx[i] + eoff[i & 7];
}

// ---------------- scatter (t,k) -> dense slots + inverse map ----------------
__global__ __launch_bounds__(256) void scatter_kernel(
    const int* __restrict__ tok_e, const int* __restrict__ tok_r, const float* __restrict__ tok_w,
    const int* __restrict__ base, int* __restrict__ slot_token, float* __restrict__ slot_w,
    int* __restrict__ tok_slot)
{
  int i = (blockIdx.x << 8) + threadIdx.x;
  int e = tok_e[i];
  int slot = base[((i >> 8) << 3) + e] + tok_r[i];
  slot_token[slot] = i >> 1;
  slot_w[slot] = tok_w[i];
  tok_slot[i] = slot;
}

// ---------------- expert_w fp32 [e][k][n] -> bf16 transposed Wt[e][n][k] ----------------
__global__ __launch_bounds__(256) void wconv_kernel(const float* __restrict__ w,
                                                    unsigned short* __restrict__ wt)
{
  __shared__ float tile[32][33];
  const float* we = w + ((size_t)blockIdx.z << 20);
  unsigned short* wte = wt + ((size_t)blockIdx.z << 20);
  int k0 = blockIdx.x << 5, n0 = blockIdx.y << 5;
  for (int i = threadIdx.x; i < 1024; i += 256) {
    int k = i >> 5, n = i & 31;
    tile[k][n] = we[(size_t)(k0 + k) * 1024 + n0 + n];
  }
  __syncthreads();
  for (int i = threadIdx.x; i < 1024; i += 256) {
    int n = i >> 5, k = i & 31;
    wte[(size_t)(n0 + n) * 1024 + k0 + k] = f2bf(tile[k][n]);
  }
}

// ---------------- grouped GEMM: 128x128 tile, BK=32, swizzled LDS, ybuf epilogue ----------
// LDS slot (row, s) holds global k-block (s ^ ((row>>1)&3)): linear glds dest +
// pre-swizzled global source + matching XOR on ds_read (both-sides rule).
__global__ __launch_bounds__(256) void moe_gemm(
    const unsigned short* __restrict__ xb, const unsigned short* __restrict__ wt,
    const float* __restrict__ bias, const int* __restrict__ ctrl,
    const int* __restrict__ slot_token, const float* __restrict__ slot_w,
    float* __restrict__ ybuf, float* __restrict__ out, int total_slots, int use_ybuf)
{
  __shared__ unsigned short Alds[128 * 32];
  __shared__ unsigned short Blds[128 * 32];
  __shared__ int   tokid[128];
  __shared__ float wrow[128];

  int by = blockIdx.y;
  if (by >= ctrl[24]) return;
  int e = 0;
  #pragma unroll
  for (int i = 1; i < 8; ++i) if (by >= ctrl[16 + i]) e = i;
  int mblk = by - ctrl[16 + e];
  int cnt  = ctrl[e];
  int off  = ctrl[8 + e];
  int slot0 = off + (mblk << 7);
  int rows_valid = cnt - (mblk << 7); if (rows_valid > 128) rows_valid = 128;

  int tid = threadIdx.x;
  if (tid < 128) {
    int s = slot0 + tid; if (s > total_slots - 1) s = total_slots - 1;
    tokid[tid] = slot_token[s];
    wrow[tid]  = slot_w[s];
  }
  __syncthreads();

  int lane = tid & 63, w = tid >> 6;
  int bn0 = blockIdx.x << 7;

  // staging: chunk c -> LDS slot c (row=c>>2, s=c&3); loads global k-block s^((row>>1)&3)
  int c0 = (w << 6) + lane, c1 = c0 + 256;
  int r0 = c0 >> 2, k0 = (c0 & 3) ^ ((r0 >> 1) & 3);
  int r1 = c1 >> 2, k1 = (c1 & 3) ^ ((r1 >> 1) & 3);
  const unsigned short* gA0 = xb + ((size_t)tokid[r0] << 10) + (k0 << 3);
  const unsigned short* gA1 = xb + ((size_t)tokid[r1] << 10) + (k1 << 3);
  const unsigned short* wte = wt + ((size_t)e << 20);
  const unsigned short* gB0 = wte + ((size_t)(bn0 + r0) << 10) + (k0 << 3);
  const unsigned short* gB1 = wte + ((size_t)(bn0 + r1) << 10) + (k1 << 3);
  unsigned short* lA0 = &Alds[(size_t)(w << 6) * 8];          // wave-uniform LDS dests
  unsigned short* lA1 = &Alds[(size_t)((w << 6) + 256) * 8];
  unsigned short* lB0 = &Blds[(size_t)(w << 6) * 8];
  unsigned short* lB1 = &Blds[(size_t)((w << 6) + 256) * 8];

  int wr = w >> 1, wc = w & 1;
  int l15 = lane & 15, hk = lane >> 4;
  f32x4_t acc[4][4] = {};

  for (int kk = 0; kk < 1024; kk += 32) {
    GLOAD_LDS16(gA0 + kk, lA0);
    GLOAD_LDS16(gA1 + kk, lA1);
    GLOAD_LDS16(gB0 + kk, lB0);
    GLOAD_LDS16(gB1 + kk, lB1);
    __syncthreads();                                     // drains vmcnt -> staging visible
    short8_t aF[4], bF[4];
    #pragma unroll
    for (int m = 0; m < 4; ++m) {
      int ar = (wr << 6) + (m << 4) + l15;
      aF[m] = *(const short8_t*)&Alds[(ar << 5) + ((hk ^ ((ar >> 1) & 3)) << 3)];
    }
    #pragma unroll
    for (int n = 0; n < 4; ++n) {
      int br = (wc << 6) + (n << 4) + l15;
      bF[n] = *(const short8_t*)&Blds[(br << 5) + ((hk ^ ((br >> 1) & 3)) << 3)];
    }
    #pragma unroll
    for (int m = 0; m < 4; ++m)
      #pragma unroll
      for (int n = 0; n < 4; ++n)
        acc[m][n] = __builtin_amdgcn_mfma_f32_16x16x32_bf16(aF[m], bF[n], acc[m][n], 0, 0, 0);
    __syncthreads();                                     // all waves done reading before overwrite
  }

  const float* be = bias + (e << 10);
  #pragma unroll
  for (int n = 0; n < 4; ++n) {
    int dout = bn0 + (wc << 6) + (n << 4) + l15;
    float bv = be[dout];
    #pragma unroll
    for (int m = 0; m < 4; ++m) {
      int rbase = (wr << 6) + (m << 4) + (hk << 2);
      #pragma unroll
      for (int r = 0; r < 4; ++r) {
        int row = rbase + r;
        if (row < rows_valid) {
          float val = wrow[row] * (acc[m][n][r] + bv);
          if (use_ybuf) ybuf[((size_t)(slot0 + row) << 10) + dout] = val;
          else atomicAdd(&out[((size_t)tokid[row] << 10) + dout], val);
        }
      }
    }
  }
}

// ---------------- combine: out[t] = ybuf[slot0(t)] + ybuf[slot1(t)] ----------------
__global__ __launch_bounds__(256) void combine_kernel(
    const float* __restrict__ ybuf, const int* __restrict__ tok_slot, float* __restrict__ out)
{
  int t = blockIdx.x;
  int s0 = tok_slot[t << 1], s1 = tok_slot[(t << 1) + 1];
  const float4* y0 = (const float4*)(ybuf + ((size_t)s0 << 10));
  const float4* y1 = (const float4*)(ybuf + ((size_t)s1 << 10));
  float4 a = y0[threadIdx.x], b = y1[threadIdx.x];
  float4 r; r.x = a.x + b.x; r.y = a.y + b.y; r.z = a.z + b.z; r.w = a.w + b.w;
  ((float4*)(out + ((size_t)t << 10)))[threadIdx.x] = r;
}

extern "C" void kernel_launch(void* const* d_in, const int* in_sizes, int n_in,
                              void* d_out, int out_size, void* d_ws, size_t ws_size,
                              hipStream_t stream) {
  (void)n_in;
  const float* x  = (const float*)d_in[0];
  const float* gw = (const float*)d_in[1];
  const float* ew = (const float*)d_in[2];
  const float* eb = (const float*)d_in[3];
  int T  = in_sizes[0] >> 10;   // 32768
  int T2 = T << 1;              // 65536 slots

  // workspace layout
  char* wsb = (char*)d_ws;
  unsigned short* xb = (unsigned short*)wsb;
  size_t off = (size_t)T * 1024 * 2;                    // x bf16: 64 MB
  unsigned short* wt = (unsigned short*)(wsb + off);
  off += (size_t)8 * 1024 * 1024 * 2;                   // Wt bf16: 16 MB
  int* ctrl = (int*)(wsb + off); off += 256;
  int* tok_e = (int*)(wsb + off); off += (size_t)T2 * 4;
  int* tok_r = (int*)(wsb + off); off += (size_t)T2 * 4;
  float* tok_w = (float*)(wsb + off); off += (size_t)T2 * 4;
  int* slot_token = (int*)(wsb + off); off += (size_t)T2 * 4;
  float* slot_w = (float*)(wsb + off); off += (size_t)T2 * 4;
  int* tok_slot = (int*)(wsb + off); off += (size_t)T2 * 4;
  int* chunkhist = (int*)(wsb + off); off += 2048 * 4;
  int* base = (int*)(wsb + off); off += 2048 * 4;
  float* ybuf = (float*)(wsb + off);
  size_t need = off + (size_t)T2 * 1024 * 4;            // +268 MB
  int use_ybuf = (ws_size >= need) ? 1 : 0;

  float* out = (float*)d_out;

  if (!use_ybuf)
    hipMemsetAsync(d_out, 0, (size_t)out_size * sizeof(float), stream);
  gate_kernel<<<T / 16, 256, 0, stream>>>(x, gw, xb, tok_e, tok_w);
  wconv_kernel<<<dim3(32, 32, 8), 256, 0, stream>>>(ew, wt);
  hist_kernel<<<T2 / 256, 256, 0, stream>>>(tok_e, tok_r, chunkhist);
  scan_kernel<<<1, 512, 0, stream>>>(chunkhist, base, ctrl);
  scatter_kernel<<<T2 / 256, 256, 0, stream>>>(tok_e, tok_r, tok_w, base,
                                               slot_token, slot_w, tok_slot);
  moe_gemm<<<dim3(8, 520), 256, 0, stream>>>(xb, wt, eb, ctrl, slot_token, slot_w,
                                             ybuf, out, T2, use_ybuf);
  if (use_ybuf)
    combine_kernel<<<T, 256, 0, stream>>>(ybuf, tok_slot, out);
}

// Round 4
// 418.021 us; speedup vs baseline: 2.9346x; 1.0517x over previous
//
#include <hip/hip_runtime.h>
#include <hip/hip_bf16.h>

// MoE top-2, T=32768 tokens, D=1024, E=8.
// Pipeline: gate(4 tok/wave) -> hist -> scan -> scatter(+inverse map) -> wconv
//           -> grouped GEMM (bf16 MFMA, swizzled LDS, XCD-grouped blocks, ybuf) -> combine.

typedef __attribute__((ext_vector_type(8))) short short8_t;
typedef __attribute__((ext_vector_type(4))) float f32x4_t;

#define GLOAD_LDS16(g, l)                                                                     \
  __builtin_amdgcn_global_load_lds((const __attribute__((address_space(1))) unsigned int*)(g), \
                                   (__attribute__((address_space(3))) unsigned int*)(l), 16, 0, 0)

__device__ __forceinline__ unsigned short f2bf(float f) {
  union { __hip_bfloat16 h; unsigned short u; } c;
  c.h = __float2bfloat16(f);
  return c.u;
}

// ---------------- gate: 4 tokens/wave; fp32 logits, top-2 softmax; x -> bf16 ----------------
__global__ __launch_bounds__(256) void gate_kernel(
    const float* __restrict__ x, const float* __restrict__ gw,
    unsigned short* __restrict__ xb,
    int* __restrict__ tok_e, float* __restrict__ tok_w)
{
  int wid = threadIdx.x >> 6, lane = threadIdx.x & 63;
  int t0 = (blockIdx.x << 4) + (wid << 2);              // 4 tokens per wave
  const float4* g4 = (const float4*)gw;                 // gw is [1024][8] row-major
  float lg[4][8] = {};
  #pragma unroll
  for (int c = 0; c < 4; ++c) {
    int d4 = (c << 6) + lane;                           // float4 index within a row
    float4 ga[4], gb[4];
    #pragma unroll
    for (int j = 0; j < 4; ++j) {
      int d = (d4 << 2) + j;
      ga[j] = g4[d << 1];
      gb[j] = g4[(d << 1) + 1];
    }
    #pragma unroll
    for (int t = 0; t < 4; ++t) {                       // reuse gw regs across 4 tokens
      const float4* x4 = (const float4*)(x + ((size_t)(t0 + t) << 10));
      float4 v = x4[d4];
      unsigned long long pk = (unsigned long long)f2bf(v.x)
                            | ((unsigned long long)f2bf(v.y) << 16)
                            | ((unsigned long long)f2bf(v.z) << 32)
                            | ((unsigned long long)f2bf(v.w) << 48);
      ((unsigned long long*)(xb + ((size_t)(t0 + t) << 10)))[d4] = pk;
      float xs[4] = {v.x, v.y, v.z, v.w};
      #pragma unroll
      for (int j = 0; j < 4; ++j) {
        lg[t][0] += xs[j]*ga[j].x; lg[t][1] += xs[j]*ga[j].y;
        lg[t][2] += xs[j]*ga[j].z; lg[t][3] += xs[j]*ga[j].w;
        lg[t][4] += xs[j]*gb[j].x; lg[t][5] += xs[j]*gb[j].y;
        lg[t][6] += xs[j]*gb[j].z; lg[t][7] += xs[j]*gb[j].w;
      }
    }
  }
  #pragma unroll
  for (int t = 0; t < 4; ++t)
    #pragma unroll
    for (int e = 0; e < 8; ++e) {
      float v = lg[t][e];
      #pragma unroll
      for (int s = 32; s > 0; s >>= 1) v += __shfl_xor(v, s, 64);
      lg[t][e] = v;
    }
  if (lane < 4) {                                       // lane t finalizes token t0+t
    int t = t0 + lane;
    float m0 = lg[lane][0], m1 = -3.4e38f; int e0 = 0, e1 = 0;
    #pragma unroll
    for (int e = 1; e < 8; ++e) {                       // strict '>' matches jax top_k ties
      float v = lg[lane][e];
      if (v > m0) { m1 = m0; e1 = e0; m0 = v; e0 = e; }
      else if (v > m1) { m1 = v; e1 = e; }
    }
    float p1 = 1.0f / (1.0f + expf(m0 - m1));
    float p0 = 1.0f - p1;
    int i0 = t << 1;
    tok_e[i0]   = e0; tok_w[i0]   = p0;
    tok_e[i0+1] = e1; tok_w[i0+1] = p1;
  }
}

// ---------------- hist: per-256-entry chunk, LDS histogram + local rank ----------------
__global__ __launch_bounds__(256) void hist_kernel(
    const int* __restrict__ tok_e, int* __restrict__ tok_r, int* __restrict__ chunkhist)
{
  __shared__ int lh[8];
  if (threadIdx.x < 8) lh[threadIdx.x] = 0;
  __syncthreads();
  int i = (blockIdx.x << 8) + threadIdx.x;
  int e = tok_e[i];
  tok_r[i] = atomicAdd(&lh[e], 1);
  __syncthreads();
  if (threadIdx.x < 8) chunkhist[(blockIdx.x << 3) + threadIdx.x] = lh[threadIdx.x];
}

// ---------------- scan: 8 waves, wave e scans expert e across 256 chunks ----------------
__global__ __launch_bounds__(512) void scan_kernel(
    const int* __restrict__ chunkhist, int* __restrict__ base, int* __restrict__ ctrl)
{
  __shared__ int h[2048];
  __shared__ int bx[2048];
  __shared__ int tot[8], eoff[8];
  for (int i = threadIdx.x; i < 2048; i += 512) h[i] = chunkhist[i];
  __syncthreads();
  int wid = threadIdx.x >> 6, lane = threadIdx.x & 63;
  int running = 0;
  #pragma unroll
  for (int b = 0; b < 4; ++b) {
    int c = (b << 6) + lane;
    int orig = h[(c << 3) + wid];
    int v = orig;
    #pragma unroll
    for (int s = 1; s < 64; s <<= 1) {
      int u = __shfl_up(v, s, 64);
      if (lane >= s) v += u;
    }
    bx[(c << 3) + wid] = running + v - orig;            // exclusive, expert-local
    running += __shfl(v, 63, 64);
  }
  if (lane == 0) tot[wid] = running;
  __syncthreads();
  if (threadIdx.x == 0) {
    int off = 0, boff = 0;
    #pragma unroll
    for (int e = 0; e < 8; ++e) {
      ctrl[e] = tot[e];
      ctrl[8 + e] = off; eoff[e] = off; off += tot[e];
      ctrl[16 + e] = boff; boff += (tot[e] + 127) >> 7;
    }
    ctrl[24] = boff;
  }
  __syncthreads();
  for (int i = threadIdx.x; i < 2048; i += 512) base[i] = bx[i] + eoff[i & 7];
}

// ---------------- scatter (t,k) -> dense slots + inverse map ----------------
__global__ __launch_bounds__(256) void scatter_kernel(
    const int* __restrict__ tok_e, const int* __restrict__ tok_r, const float* __restrict__ tok_w,
    const int* __restrict__ base, int* __restrict__ slot_token, float* __restrict__ slot_w,
    int* __restrict__ tok_slot)
{
  int i = (blockIdx.x << 8) + threadIdx.x;
  int e = tok_e[i];
  int slot = base[((i >> 8) << 3) + e] + tok_r[i];
  slot_token[slot] = i >> 1;
  slot_w[slot] = tok_w[i];
  tok_slot[i] = slot;
}

// ---------------- expert_w fp32 [e][k][n] -> bf16 transposed Wt[e][n][k] ----------------
__global__ __launch_bounds__(256) void wconv_kernel(const float* __restrict__ w,
                                                    unsigned short* __restrict__ wt)
{
  __shared__ float tile[32][33];
  const float* we = w + ((size_t)blockIdx.z << 20);
  unsigned short* wte = wt + ((size_t)blockIdx.z << 20);
  int k0 = blockIdx.x << 5, n0 = blockIdx.y << 5;
  for (int i = threadIdx.x; i < 1024; i += 256) {
    int k = i >> 5, n = i & 31;
    tile[k][n] = we[(size_t)(k0 + k) * 1024 + n0 + n];
  }
  __syncthreads();
  for (int i = threadIdx.x; i < 1024; i += 256) {
    int n = i >> 5, k = i & 31;
    wte[(size_t)(n0 + n) * 1024 + k0 + k] = f2bf(tile[k][n]);
  }
}

// ---------------- grouped GEMM: 128x128 tile, BK=32, swizzled LDS, ybuf epilogue ----------
// 1-D grid with XCD-grouping: the 8 N-blocks of an M-group land on ONE XCD in
// consecutive dispatch slots -> shared A-panel is L2-resident (fetch 1x not 8x).
// LDS slot (row, s) holds global k-block (s ^ ((row>>1)&3)): linear glds dest +
// pre-swizzled global source + matching XOR on ds_read (both-sides rule).
__global__ __launch_bounds__(256) void moe_gemm(
    const unsigned short* __restrict__ xb, const unsigned short* __restrict__ wt,
    const float* __restrict__ bias, const int* __restrict__ ctrl,
    const int* __restrict__ slot_token, const float* __restrict__ slot_w,
    float* __restrict__ ybuf, float* __restrict__ out, int total_slots, int use_ybuf)
{
  __shared__ unsigned short Alds[128 * 32];
  __shared__ unsigned short Blds[128 * 32];
  __shared__ int   tokid[128];
  __shared__ float wrow[128];

  // bijective dispatch->(M-group, N-block) map; 8 N-blocks of a group share an XCD
  int d = blockIdx.x;
  int s_ = d >> 3, xcd = d & 7;
  int by = ((s_ >> 3) << 3) | xcd;                      // M-group 0..519
  int bx = s_ & 7;                                      // N-block 0..7

  if (by >= ctrl[24]) return;
  int e = 0;
  #pragma unroll
  for (int i = 1; i < 8; ++i) if (by >= ctrl[16 + i]) e = i;
  int mblk = by - ctrl[16 + e];
  int cnt  = ctrl[e];
  int off  = ctrl[8 + e];
  int slot0 = off + (mblk << 7);
  int rows_valid = cnt - (mblk << 7); if (rows_valid > 128) rows_valid = 128;

  int tid = threadIdx.x;
  if (tid < 128) {
    int s = slot0 + tid; if (s > total_slots - 1) s = total_slots - 1;
    tokid[tid] = slot_token[s];
    wrow[tid]  = slot_w[s];
  }
  __syncthreads();

  int lane = tid & 63, w = tid >> 6;
  int bn0 = bx << 7;

  // staging: chunk c -> LDS slot c (row=c>>2, s=c&3); loads global k-block s^((row>>1)&3)
  int c0 = (w << 6) + lane, c1 = c0 + 256;
  int r0 = c0 >> 2, k0 = (c0 & 3) ^ ((r0 >> 1) & 3);
  int r1 = c1 >> 2, k1 = (c1 & 3) ^ ((r1 >> 1) & 3);
  const unsigned short* gA0 = xb + ((size_t)tokid[r0] << 10) + (k0 << 3);
  const unsigned short* gA1 = xb + ((size_t)tokid[r1] << 10) + (k1 << 3);
  const unsigned short* wte = wt + ((size_t)e << 20);
  const unsigned short* gB0 = wte + ((size_t)(bn0 + r0) << 10) + (k0 << 3);
  const unsigned short* gB1 = wte + ((size_t)(bn0 + r1) << 10) + (k1 << 3);
  unsigned short* lA0 = &Alds[(size_t)(w << 6) * 8];          // wave-uniform LDS dests
  unsigned short* lA1 = &Alds[(size_t)((w << 6) + 256) * 8];
  unsigned short* lB0 = &Blds[(size_t)(w << 6) * 8];
  unsigned short* lB1 = &Blds[(size_t)((w << 6) + 256) * 8];

  int wr = w >> 1, wc = w & 1;
  int l15 = lane & 15, hk = lane >> 4;
  f32x4_t acc[4][4] = {};

  for (int kk = 0; kk < 1024; kk += 32) {
    GLOAD_LDS16(gA0 + kk, lA0);
    GLOAD_LDS16(gA1 + kk, lA1);
    GLOAD_LDS16(gB0 + kk, lB0);
    GLOAD_LDS16(gB1 + kk, lB1);
    __syncthreads();                                     // drains vmcnt -> staging visible
    short8_t aF[4], bF[4];
    #pragma unroll
    for (int m = 0; m < 4; ++m) {
      int ar = (wr << 6) + (m << 4) + l15;
      aF[m] = *(const short8_t*)&Alds[(ar << 5) + ((hk ^ ((ar >> 1) & 3)) << 3)];
    }
    #pragma unroll
    for (int n = 0; n < 4; ++n) {
      int br = (wc << 6) + (n << 4) + l15;
      bF[n] = *(const short8_t*)&Blds[(br << 5) + ((hk ^ ((br >> 1) & 3)) << 3)];
    }
    #pragma unroll
    for (int m = 0; m < 4; ++m)
      #pragma unroll
      for (int n = 0; n < 4; ++n)
        acc[m][n] = __builtin_amdgcn_mfma_f32_16x16x32_bf16(aF[m], bF[n], acc[m][n], 0, 0, 0);
    __syncthreads();                                     // all waves done reading before overwrite
  }

  const float* be = bias + (e << 10);
  #pragma unroll
  for (int n = 0; n < 4; ++n) {
    int dout = bn0 + (wc << 6) + (n << 4) + l15;
    float bv = be[dout];
    #pragma unroll
    for (int m = 0; m < 4; ++m) {
      int rbase = (wr << 6) + (m << 4) + (hk << 2);
      #pragma unroll
      for (int r = 0; r < 4; ++r) {
        int row = rbase + r;
        if (row < rows_valid) {
          float val = wrow[row] * (acc[m][n][r] + bv);
          if (use_ybuf) ybuf[((size_t)(slot0 + row) << 10) + dout] = val;
          else atomicAdd(&out[((size_t)tokid[row] << 10) + dout], val);
        }
      }
    }
  }
}

// ---------------- combine: out[t] = ybuf[slot0(t)] + ybuf[slot1(t)] ----------------
__global__ __launch_bounds__(256) void combine_kernel(
    const float* __restrict__ ybuf, const int* __restrict__ tok_slot, float* __restrict__ out)
{
  int t = blockIdx.x;
  int s0 = tok_slot[t << 1], s1 = tok_slot[(t << 1) + 1];
  const float4* y0 = (const float4*)(ybuf + ((size_t)s0 << 10));
  const float4* y1 = (const float4*)(ybuf + ((size_t)s1 << 10));
  float4 a = y0[threadIdx.x], b = y1[threadIdx.x];
  float4 r; r.x = a.x + b.x; r.y = a.y + b.y; r.z = a.z + b.z; r.w = a.w + b.w;
  ((float4*)(out + ((size_t)t << 10)))[threadIdx.x] = r;
}

extern "C" void kernel_launch(void* const* d_in, const int* in_sizes, int n_in,
                              void* d_out, int out_size, void* d_ws, size_t ws_size,
                              hipStream_t stream) {
  (void)n_in;
  const float* x  = (const float*)d_in[0];
  const float* gw = (const float*)d_in[1];
  const float* ew = (const float*)d_in[2];
  const float* eb = (const float*)d_in[3];
  int T  = in_sizes[0] >> 10;   // 32768
  int T2 = T << 1;              // 65536 slots

  // workspace layout
  char* wsb = (char*)d_ws;
  unsigned short* xb = (unsigned short*)wsb;
  size_t off = (size_t)T * 1024 * 2;                    // x bf16: 64 MB
  unsigned short* wt = (unsigned short*)(wsb + off);
  off += (size_t)8 * 1024 * 1024 * 2;                   // Wt bf16: 16 MB
  int* ctrl = (int*)(wsb + off); off += 256;
  int* tok_e = (int*)(wsb + off); off += (size_t)T2 * 4;
  int* tok_r = (int*)(wsb + off); off += (size_t)T2 * 4;
  float* tok_w = (float*)(wsb + off); off += (size_t)T2 * 4;
  int* slot_token = (int*)(wsb + off); off += (size_t)T2 * 4;
  float* slot_w = (float*)(wsb + off); off += (size_t)T2 * 4;
  int* tok_slot = (int*)(wsb + off); off += (size_t)T2 * 4;
  int* chunkhist = (int*)(wsb + off); off += 2048 * 4;
  int* base = (int*)(wsb + off); off += 2048 * 4;
  float* ybuf = (float*)(wsb + off);
  size_t need = off + (size_t)T2 * 1024 * 4;            // +268 MB
  int use_ybuf = (ws_size >= need) ? 1 : 0;

  float* out = (float*)d_out;

  if (!use_ybuf)
    hipMemsetAsync(d_out, 0, (size_t)out_size * sizeof(float), stream);
  gate_kernel<<<T / 16, 256, 0, stream>>>(x, gw, xb, tok_e, tok_w);
  wconv_kernel<<<dim3(32, 32, 8), 256, 0, stream>>>(ew, wt);
  hist_kernel<<<T2 / 256, 256, 0, stream>>>(tok_e, tok_r, chunkhist);
  scan_kernel<<<1, 512, 0, stream>>>(chunkhist, base, ctrl);
  scatter_kernel<<<T2 / 256, 256, 0, stream>>>(tok_e, tok_r, tok_w, base,
                                               slot_token, slot_w, tok_slot);
  moe_gemm<<<4160, 256, 0, stream>>>(xb, wt, eb, ctrl, slot_token, slot_w,
                                     ybuf, out, T2, use_ybuf);
  if (use_ybuf)
    combine_kernel<<<T, 256, 0, stream>>>(ybuf, tok_slot, out);
}